// Round 1
// 72.918 us; speedup vs baseline: 1.0119x; 1.0119x over previous
//
#include <hip/hip_runtime.h>

// Problem constants (from reference setup_inputs):
//   pred:      [64, 4]     fp32  (d_in[0])
//   fragments: [32, 64, 2] fp32  (d_in[1]) -> 2048 points
//   boundary:  [1, 400, 2] fp32  (d_in[2])
//   out: scalar fp32 = sum_pts min_b( sqdist(pt, box_b boundary) * outside_b ) / 64
#define NBOX 64
#define BP   400
#define NPTS 2048
#define FP   64

// K1: one block per fragment point, 256 thr = 4 waves.
// lane (t&63) owns box (t&63) (same mapping in every wave -> block-uniform
// ballot); wave (t>>6) covers a 100-sample chunk of BP.
// Instead of atomicAdd to a single global address (~350 device-scope atomics
// to ONE cacheline, serialized across 8 non-coherent XCDs), every block
// plain-stores its per-point contribution (or 0) to ws[pt]. All 2048 slots
// are written each call, so the 0xAA ws-poison is never observed.
__global__ __launch_bounds__(256) void point_min_kernel(
    const float* __restrict__ pred,      // [64*4]
    const float* __restrict__ frags,     // [2048*2]
    const float* __restrict__ boundary,  // [400*2]
    float* __restrict__ ws)              // [2048] per-point min (0 if inside)
{
    const int t  = threadIdx.x;
    const int pt = blockIdx.x;
    const int b  = t & 63;   // box index
    const int j  = t >> 6;   // wave id = BP chunk

    const float px = frags[2 * pt + 0];
    const float py = frags[2 * pt + 1];

    const float lox = pred[4 * b + 0];
    const float loy = pred[4 * b + 1];
    const float hix = pred[4 * b + 2];
    const float hiy = pred[4 * b + 3];

    const bool inside = (px >= lox) && (py >= loy) && (hix >= px) && (hiy >= py);
    // Identical ballot in all 4 waves -> block-uniform branch (safe vs barrier).
    if (__ballot(inside) != 0ULL) {      // contribution exactly 0
        if (t == 0) ws[pt] = 0.0f;
        return;
    }

    // Stage boundary into LDS: 800 floats = 200 float4, one vec-load per thread.
    __shared__ float4 s_bnd4[BP / 2];        // 200 float4 = 400 (x,y) pairs
    __shared__ float  s_red[256];
    if (t < BP / 2) s_bnd4[t] = ((const float4*)boundary)[t];
    __syncthreads();

    const float whx = hix - lox;
    const float why = hiy - loy;
    const float ax  = px - lox;              // dx = ax - bx*whx
    const float ay  = py - loy;

    const float2* s_bnd = (const float2*)s_bnd4;
    float mind = 1e30f;
    const int k0 = j * (BP / 4);
    #pragma unroll 5
    for (int k = 0; k < BP / 4; ++k) {
        const float2 bxy = s_bnd[k0 + k];    // wave-uniform addr -> broadcast
        const float dx = fmaf(-whx, bxy.x, ax);
        const float dy = fmaf(-why, bxy.y, ay);
        const float d  = fmaf(dy, dy, dx * dx);
        mind = fminf(mind, d);
    }

    // Min across the 4 waves per box (LDS), then across 64 boxes (shuffle).
    s_red[t] = mind;
    __syncthreads();
    if (t < 64) {
        float v = fminf(fminf(s_red[t], s_red[t + 64]),
                        fminf(s_red[t + 128], s_red[t + 192]));
        #pragma unroll
        for (int off = 32; off; off >>= 1)
            v = fminf(v, __shfl_down(v, off));
        if (t == 0) ws[pt] = v;              // plain store, no atomic
    }
}

// K2: one block sums ws[0..2047] and writes out = sum / FP. Deterministic
// tree reduction (replaces the random-order atomic accumulation).
__global__ __launch_bounds__(256) void reduce_kernel(
    const float* __restrict__ ws,        // [2048]
    float* __restrict__ out)             // [1]
{
    const int t = threadIdx.x;
    // 2048 floats = 512 float4; 256 threads x 2 float4 each.
    const float4* w4 = (const float4*)ws;
    const float4 a = w4[t];
    const float4 c = w4[t + 256];
    float s = (a.x + a.y) + (a.z + a.w) + (c.x + c.y) + (c.z + c.w);
    #pragma unroll
    for (int off = 32; off; off >>= 1)
        s += __shfl_down(s, off);
    __shared__ float sr[4];
    if ((t & 63) == 0) sr[t >> 6] = s;
    __syncthreads();
    if (t == 0)
        out[0] = (sr[0] + sr[1] + sr[2] + sr[3]) * (1.0f / (float)FP);
}

extern "C" void kernel_launch(void* const* d_in, const int* in_sizes, int n_in,
                              void* d_out, int out_size, void* d_ws, size_t ws_size,
                              hipStream_t stream) {
    const float* pred     = (const float*)d_in[0];
    const float* frags    = (const float*)d_in[1];
    const float* boundary = (const float*)d_in[2];
    float* ws  = (float*)d_ws;
    float* out = (float*)d_out;

    // No memset node: out is written unconditionally by reduce_kernel, and
    // every ws slot K2 reads is written by K1 first.
    point_min_kernel<<<NPTS, 256, 0, stream>>>(pred, frags, boundary, ws);
    reduce_kernel<<<1, 256, 0, stream>>>(ws, out);
}